// Round 4
// baseline (135.245 us; speedup 1.0000x reference)
//
#include <hip/hip_runtime.h>

// DeepFM fused kernel for MI355X (gfx950) — round 15.
// A-path theory, third iteration. A bytes/block were 1152 KB served at
// ~19-21 B/cyc/CU (~25 us of main's 40). This round:
//  1) aux dedup: waves wi<4 own 2 rt-tiles of aux each (axc0/axc1);
//     aux A reads 256->128 KB/block (was read 4x redundantly).
//  2) phase-3 rewrite: 8 waves x ftw=w x rt0..3; W2 reads 128->64 KB.
//  3) nontemporal loads on ALL ws A-frag reads (single-use per CU, ws
//     rewritten every iteration -> L1/L2 allocation is pure waste; if the
//     per-CU L1 fill path is the ~19 B/cyc cap, nt lifts it).
//  4) depth-2 A prefetch in phases 2/3 (registers free there).
// Structure otherwise R14: RB=64, NTH=1024, 1 block/CU, K-rotation, T14
// input prefetch, staggered pf conversion, waves_per_eu(4,4).

#define NTH 1024
#define RB  64

typedef __bf16 bf16x8 __attribute__((ext_vector_type(8)));
typedef float  f32x4  __attribute__((ext_vector_type(4)));

// workspace layout (bytes)
#define WS_WMF  0            // movie tower A-frags [16 kg][18 ft][64][16B]
#define WS_WUF  294912
#define WS_W1F  589824       // [16 kg][16 ft][64][16B]
#define WS_W2F  851968       // [8 kg][8 ft][64][16B]
#define WS_BIAS 917504       // fp32 bms[16] bus[16] badd

// LDS layout (bytes)
#define BPITCH  528          // 256 bf16 (half K) + 16B pad per row
#define L_BST   0            // bstage: 128 rows x 528 = 67584 (h1frag aliases)
#define L_DENSE 67584        // densefrag [16kg][4rt][64][16] = 65536
#define L_FM    133120       // fmbuf [2][64][17] f32 = 8704
#define L_ADD   141824       // addbuf [2][64] f32 = 512
#define L_OUT   142336       // outpart[64] f32 = 256
#define LDSB    142592

__device__ __forceinline__ unsigned short f2bf(float f) {
  unsigned u = __builtin_bit_cast(unsigned, f);
  u += 0x7FFFu + ((u >> 16) & 1u);           // RNE
  return (unsigned short)(u >> 16);
}

__device__ __forceinline__ f32x4 mfma_bf16(bf16x8 a, bf16x8 b, f32x4 c) {
  return __builtin_amdgcn_mfma_f32_16x16x32_bf16(a, b, c, 0, 0, 0);
}

// non-temporal A-frag load: single-use data, skip cache allocation
__device__ __forceinline__ bf16x8 ldnt(const char* p) {
  return __builtin_nontemporal_load((const bf16x8*)p);
}

// ---------------------------------------------------------------------------
// Prep: fragment-ordered bf16 weights + bias aux. Tower features:
// f<256 raw col f; 256..271 = sum_i W[:, i*16+(f-256)] (FM col sums);
// 272 = W[:,256] (additive); 273..287 = 0.  4 units per 256-thread block.
// ---------------------------------------------------------------------------
extern "C" __global__ __launch_bounds__(256) void deepfm_prep(
    const float* __restrict__ Wm, const float* __restrict__ bm,
    const float* __restrict__ Wu, const float* __restrict__ bu,
    const float* __restrict__ W1, const float* __restrict__ W2,
    const float* __restrict__ b3, char* __restrict__ ws) {
  const int unit = blockIdx.x * 4 + (threadIdx.x >> 6);
  if (unit >= 897) return;
  const int l = threadIdx.x & 63;
  const int fi = l & 15, q = l >> 4;
  unsigned short h[8];
  if (unit < 576) {                      // towers: 2 x 16 kg x 18 ft
    const int t = unit / 288, rem = unit % 288;
    const int kg = rem / 18, ft = rem % 18;
    const float* W = t ? Wu : Wm;
    char* outp = ws + (t ? WS_WUF : WS_WMF);
    const int f = ft * 16 + fi;
#pragma unroll
    for (int e = 0; e < 8; ++e) {
      const int k = kg * 32 + q * 8 + e;
      float val;
      if (f < 256) val = W[k * 257 + f];
      else if (f < 272) {
        float s = 0.f;
#pragma unroll
        for (int i = 0; i < 16; ++i) s += W[k * 257 + i * 16 + (f - 256)];
        val = s;
      } else if (f == 272) val = W[k * 257 + 256];
      else val = 0.f;
      h[e] = f2bf(val);
    }
    uint4 o;
    o.x = h[0] | ((unsigned)h[1] << 16); o.y = h[2] | ((unsigned)h[3] << 16);
    o.z = h[4] | ((unsigned)h[5] << 16); o.w = h[6] | ((unsigned)h[7] << 16);
    *(uint4*)(outp + (((kg * 18 + ft) * 64 + l) << 4)) = o;
  } else if (unit < 832) {               // W1: 16 kg x 16 ft
    const int bb = unit - 576;
    const int kg = bb / 16, ft = bb % 16;
    const int f = ft * 16 + fi;
#pragma unroll
    for (int e = 0; e < 8; ++e) h[e] = f2bf(W1[(kg * 32 + q * 8 + e) * 256 + f]);
    uint4 o;
    o.x = h[0] | ((unsigned)h[1] << 16); o.y = h[2] | ((unsigned)h[3] << 16);
    o.z = h[4] | ((unsigned)h[5] << 16); o.w = h[6] | ((unsigned)h[7] << 16);
    *(uint4*)(ws + WS_W1F + (((kg * 16 + ft) * 64 + l) << 4)) = o;
  } else if (unit < 896) {               // W2: 8 kg x 8 ft
    const int bb = unit - 832;
    const int kg = bb / 8, ft = bb % 8;
    const int f = ft * 16 + fi;
#pragma unroll
    for (int e = 0; e < 8; ++e) h[e] = f2bf(W2[(kg * 32 + q * 8 + e) * 128 + f]);
    uint4 o;
    o.x = h[0] | ((unsigned)h[1] << 16); o.y = h[2] | ((unsigned)h[3] << 16);
    o.z = h[4] | ((unsigned)h[5] << 16); o.w = h[6] | ((unsigned)h[7] << 16);
    *(uint4*)(ws + WS_W2F + (((kg * 8 + ft) * 64 + l) << 4)) = o;
  } else {                               // bias aux
    float* aux = (float*)(ws + WS_BIAS);
    if (l < 16) {
      float s = 0.f;
      for (int i = 0; i < 16; ++i) s += bm[i * 16 + l];
      aux[l] = s;
    } else if (l < 32) {
      const int k = l - 16;
      float s = 0.f;
      for (int i = 0; i < 16; ++i) s += bu[i * 16 + k];
      aux[l] = s;
    } else if (l == 32) {
      aux[32] = bm[256] + bu[256] + b3[0];
    }
  }
}

// ---------------------------------------------------------------------------
// Main fused kernel. 64 rows/block, 16 waves.
// Phase 1: tw = w>>3 (tower), wi = w&7. Wave owns ft tiles {wi*2, wi*2+1},
// rt 0..3. Aux dedup: waves wi<4 own axi=wi&1 (0: FM col sums, 1: additive)
// for rt pair rtb=(wi>>1)*2. K in 2 staged halves (order rotated per
// block); T14 input prefetch with staggered conversion; compute-h1 has
// 1-deep manual A prefetch. All ws A-frag loads nontemporal.
// Phase 2: wave w owns ft=w (of 16), rt 0..3, depth-2 A prefetch.
// Phase 3: wave w<8 owns ft=w (of 8), rt 0..3, depth-2 A prefetch.
// ---------------------------------------------------------------------------
extern "C" __global__ __launch_bounds__(NTH)
__attribute__((amdgpu_waves_per_eu(4, 4))) void deepfm_main(
    const float* __restrict__ movie, const float* __restrict__ user,
    const float* __restrict__ bm, const float* __restrict__ bu,
    const float* __restrict__ b1, const float* __restrict__ b2,
    const float* __restrict__ W3, const char* __restrict__ ws,
    float* __restrict__ out) {
  extern __shared__ __align__(16) char lds[];
  char* const bstage    = lds + L_BST;     // 128 rows (both towers), half K
  char* const densefrag = lds + L_DENSE;   // [16kg][4rt][64][16]
  char* const h1frag    = lds + L_BST;     // phases 2/3 (aliases bstage)
  float* const fmbuf    = (float*)(lds + L_FM);   // [2][64][17]
  float* const addbuf   = (float*)(lds + L_ADD);  // [2][64]
  float* const outpart  = (float*)(lds + L_OUT);

  const int tid = threadIdx.x;
  const int w   = tid >> 6;        // 0..15
  const int l   = tid & 63;
  const int cn  = l & 15;
  const int q   = l >> 4;
  const int row0 = blockIdx.x * RB;

  const int tw   = w >> 3;         // tower this wave computes in phase 1
  const int wi   = w & 7;
  const int axi  = wi & 1;         // (wi<4) 0: FM col sums, 1: additive
  const int rtb  = (wi >> 1) * 2;  // (wi<4) rt pair base: 0 or 2

  // per-block rotation seeds (blocks on one XCD have distinct rot)
  const int rot  = (int)blockIdx.x >> 3;
  const int hord = rot & 1;                // phase-1 half order
  const int kk0  = (rot >> 1) & 7;         // phase-1 kgl start
  const int p2r  = rot & 15;               // phase-2 kg start
  const int p3r  = rot & 7;                // phase-3 kg start

  const f32x4 zz = {0.f, 0.f, 0.f, 0.f};
  const float* auxb = (const float*)(ws + WS_BIAS);

  bf16x8 p2a, p2b;   // phase-2 first two A-frags (prefetched across barrier)
  bf16x8 p3a, p3b;   // phase-3 first two A-frags

  // ---------------- Phase 1: both towers in parallel, K in 2 staged halves
  {
    const char* WF = ws + (tw ? WS_WUF : WS_WMF);
    const char* brow = bstage + tw * 64 * BPITCH;
    f32x4 a0r0 = zz, a0r1 = zz, a0r2 = zz, a0r3 = zz;
    f32x4 a1r0 = zz, a1r1 = zz, a1r2 = zz, a1r3 = zz;
    f32x4 axc0 = zz, axc1 = zz;

    const int h0 = hord, h1h = hord ^ 1;

    // stage half h0: 128 rows x 256 cols fp32 -> bf16, coalesced
#pragma unroll
    for (int p = 0; p < 8; ++p) {
      const int idx = p * 1024 + tid;    // float4 id
      const int rr = idx >> 6, f4 = idx & 63;
      const float* src = (rr >= 64) ? user : movie;
      const float4 v = *(const float4*)(src + (size_t)(row0 + (rr & 63)) * 512 +
                                        h0 * 256 + f4 * 4);
      uint2 o;
      o.x = f2bf(v.x) | ((unsigned)f2bf(v.y) << 16);
      o.y = f2bf(v.z) | ((unsigned)f2bf(v.w) << 16);
      *(uint2*)(bstage + rr * BPITCH + f4 * 8) = o;
    }
    __syncthreads();

    // T14: issue half-h1 global loads now; they land during compute(h0)
    float4 pf[8];
#pragma unroll
    for (int p = 0; p < 8; ++p) {
      const int idx = p * 1024 + tid;
      const int rr = idx >> 6, f4 = idx & 63;
      const float* src = (rr >= 64) ? user : movie;
      pf[p] = *(const float4*)(src + (size_t)(row0 + (rr & 63)) * 512 +
                               h1h * 256 + f4 * 4);
    }
    uint2 pfc[8];

    // compute half h0; in-iteration A loads; staggered pf conversion
#pragma unroll
    for (int i = 0; i < 8; ++i) {
      const int kgl = (kk0 + i) & 7;
      const int kg  = h0 * 8 + kgl;
      const bf16x8 bf0 = *(const bf16x8*)(brow + cn * BPITCH + kgl * 64 + q * 16);
      const bf16x8 bf1 = *(const bf16x8*)(brow + (16 + cn) * BPITCH + kgl * 64 + q * 16);
      const bf16x8 bf2 = *(const bf16x8*)(brow + (32 + cn) * BPITCH + kgl * 64 + q * 16);
      const bf16x8 bf3 = *(const bf16x8*)(brow + (48 + cn) * BPITCH + kgl * 64 + q * 16);
      const bf16x8 A0 = ldnt(WF + (((kg * 18 + wi * 2 + 0) * 64 + l) << 4));
      const bf16x8 A1 = ldnt(WF + (((kg * 18 + wi * 2 + 1) * 64 + l) << 4));
      bf16x8 AX;
      if (wi < 4) AX = ldnt(WF + (((kg * 18 + 16 + axi) * 64 + l) << 4));
      __builtin_amdgcn_s_setprio(1);
      a0r0 = mfma_bf16(A0, bf0, a0r0);  a0r1 = mfma_bf16(A0, bf1, a0r1);
      a0r2 = mfma_bf16(A0, bf2, a0r2);  a0r3 = mfma_bf16(A0, bf3, a0r3);
      a1r0 = mfma_bf16(A1, bf0, a1r0);  a1r1 = mfma_bf16(A1, bf1, a1r1);
      a1r2 = mfma_bf16(A1, bf2, a1r2);  a1r3 = mfma_bf16(A1, bf3, a1r3);
      if (wi < 4) {
        const bf16x8 bs0 = rtb ? bf2 : bf0;
        const bf16x8 bs1 = rtb ? bf3 : bf1;
        axc0 = mfma_bf16(AX, bs0, axc0);
        axc1 = mfma_bf16(AX, bs1, axc1);
      }
      __builtin_amdgcn_s_setprio(0);
      if (i >= 1) {
        const int j = i - 1;               // static after unroll
        pfc[j].x = f2bf(pf[j].x) | ((unsigned)f2bf(pf[j].y) << 16);
        pfc[j].y = f2bf(pf[j].z) | ((unsigned)f2bf(pf[j].w) << 16);
      }
    }
    pfc[7].x = f2bf(pf[7].x) | ((unsigned)f2bf(pf[7].y) << 16);
    pfc[7].y = f2bf(pf[7].z) | ((unsigned)f2bf(pf[7].w) << 16);

    __syncthreads();   // half-h0 reads done before overwrite

    // issue first h1 kstep's A-frags; they fly under the LDS writes+barrier
    bf16x8 A0c = ldnt(WF + ((((h1h * 8 + kk0) * 18 + wi * 2 + 0) * 64 + l) << 4));
    bf16x8 A1c = ldnt(WF + ((((h1h * 8 + kk0) * 18 + wi * 2 + 1) * 64 + l) << 4));

    // write prefetched half h1 (already bf16) to LDS
#pragma unroll
    for (int p = 0; p < 8; ++p) {
      const int idx = p * 1024 + tid;
      const int rr = idx >> 6, f4 = idx & 63;
      *(uint2*)(bstage + rr * BPITCH + f4 * 8) = pfc[p];
    }
    __syncthreads();

    // compute half h1: manual 1-deep A prefetch (pf regs dead now)
#pragma unroll
    for (int i = 0; i < 8; ++i) {
      const int kgl = (kk0 + i) & 7;
      const int kg  = h1h * 8 + kgl;
      const bf16x8 bf0 = *(const bf16x8*)(brow + cn * BPITCH + kgl * 64 + q * 16);
      const bf16x8 bf1 = *(const bf16x8*)(brow + (16 + cn) * BPITCH + kgl * 64 + q * 16);
      const bf16x8 bf2 = *(const bf16x8*)(brow + (32 + cn) * BPITCH + kgl * 64 + q * 16);
      const bf16x8 bf3 = *(const bf16x8*)(brow + (48 + cn) * BPITCH + kgl * 64 + q * 16);
      bf16x8 AX;
      if (wi < 4) AX = ldnt(WF + (((kg * 18 + 16 + axi) * 64 + l) << 4));
      bf16x8 A0n, A1n;
      if (i < 7) {
        const int nkg = h1h * 8 + ((kk0 + i + 1) & 7);
        A0n = ldnt(WF + (((nkg * 18 + wi * 2 + 0) * 64 + l) << 4));
        A1n = ldnt(WF + (((nkg * 18 + wi * 2 + 1) * 64 + l) << 4));
      } else {
        A0n = A0c; A1n = A1c;
      }
      __builtin_amdgcn_s_setprio(1);
      a0r0 = mfma_bf16(A0c, bf0, a0r0);  a0r1 = mfma_bf16(A0c, bf1, a0r1);
      a0r2 = mfma_bf16(A0c, bf2, a0r2);  a0r3 = mfma_bf16(A0c, bf3, a0r3);
      a1r0 = mfma_bf16(A1c, bf0, a1r0);  a1r1 = mfma_bf16(A1c, bf1, a1r1);
      a1r2 = mfma_bf16(A1c, bf2, a1r2);  a1r3 = mfma_bf16(A1c, bf3, a1r3);
      if (wi < 4) {
        const bf16x8 bs0 = rtb ? bf2 : bf0;
        const bf16x8 bs1 = rtb ? bf3 : bf1;
        axc0 = mfma_bf16(AX, bs0, axc0);
        axc1 = mfma_bf16(AX, bs1, axc1);
      }
      __builtin_amdgcn_s_setprio(0);
      A0c = A0n; A1c = A1n;
    }

    // prefetch phase-2 first A-frags; fly under writeback + barrier + FM
    p2a = ldnt(ws + WS_W1F + (((p2r * 16 + w) * 64 + l) << 4));
    p2b = ldnt(ws + WS_W1F + (((((p2r + 1) & 15) * 16 + w) * 64 + l) << 4));

    // writeback dense feats (+tower bias, no relu) into densefrag
    const float* bt = tw ? bu : bm;
    const f32x4 accA[2][4] = {{a0r0, a0r1, a0r2, a0r3}, {a1r0, a1r1, a1r2, a1r3}};
#pragma unroll
    for (int s = 0; s < 2; ++s) {
      const int ft = wi * 2 + s;
      const int fb = ft * 16 + q * 4;
      const float g0 = bt[fb], g1 = bt[fb + 1], g2 = bt[fb + 2], g3 = bt[fb + 3];
      const int kd = tw * 256 + fb;
      const int kgd = kd >> 5, qd = (kd >> 3) & 3, ed = kd & 4;
#pragma unroll
      for (int rt = 0; rt < 4; ++rt) {
        const f32x4 v = accA[s][rt];
        uint2 p;
        p.x = f2bf(v[0] + g0) | ((unsigned)f2bf(v[1] + g1) << 16);
        p.y = f2bf(v[2] + g2) | ((unsigned)f2bf(v[3] + g3) << 16);
        *(uint2*)(densefrag + (((kgd * 4 + rt) * 64 + qd * 16 + cn) << 4) +
                  (ed ? 8 : 0)) = p;
      }
    }

    // aux writeback (dedup'd): wi<4 own rt pair {rtb, rtb+1}
    if (wi < 4) {
      if (axi == 0) {
#pragma unroll
        for (int reg = 0; reg < 4; ++reg) {
          fmbuf[(tw * 64 + rtb * 16 + cn) * 17 + (q * 4 + reg)] = axc0[reg];
          fmbuf[(tw * 64 + (rtb + 1) * 16 + cn) * 17 + (q * 4 + reg)] = axc1[reg];
        }
      } else if (q == 0) {
        addbuf[tw * 64 + rtb * 16 + cn] = axc0[0];
        addbuf[tw * 64 + (rtb + 1) * 16 + cn] = axc1[0];
      }
    }
  }

  __syncthreads();   // densefrag + fmbuf/addbuf complete; bstage dead

  // ---------------- FM epilogue: out_partial = <ms+bms, us+bus> + additive
  if (tid < 64) {
    float p = 0.f;
#pragma unroll
    for (int k = 0; k < 16; ++k)
      p += (fmbuf[tid * 17 + k] + auxb[k]) *
           (fmbuf[(64 + tid) * 17 + k] + auxb[16 + k]);
    outpart[tid] = p + addbuf[tid] + addbuf[64 + tid] + auxb[32];
  }

  // ---------------- Phase 2: h1 = relu(all_dense @ W1 + b1)
  {
    const char* W1F = ws + WS_W1F;
    bf16x8 a0c = p2a;
    bf16x8 a0n = p2b;
    f32x4 r0 = zz, r1 = zz, r2 = zz, r3 = zz;
#pragma unroll
    for (int i = 0; i < 16; ++i) {
      const int kg = (p2r + i) & 15;
      const bf16x8 b0 = *(const bf16x8*)(densefrag + (((kg * 4 + 0) * 64 + l) << 4));
      const bf16x8 b1f = *(const bf16x8*)(densefrag + (((kg * 4 + 1) * 64 + l) << 4));
      const bf16x8 b2f = *(const bf16x8*)(densefrag + (((kg * 4 + 2) * 64 + l) << 4));
      const bf16x8 b3f = *(const bf16x8*)(densefrag + (((kg * 4 + 3) * 64 + l) << 4));
      bf16x8 a2;
      if (i < 14) {
        const int nkg = (p2r + i + 2) & 15;
        a2 = ldnt(W1F + (((nkg * 16 + w) * 64 + l) << 4));
      }
      __builtin_amdgcn_s_setprio(1);
      r0 = mfma_bf16(a0c, b0,  r0);
      r1 = mfma_bf16(a0c, b1f, r1);
      r2 = mfma_bf16(a0c, b2f, r2);
      r3 = mfma_bf16(a0c, b3f, r3);
      __builtin_amdgcn_s_setprio(0);
      a0c = a0n;
      if (i < 14) a0n = a2;
    }

    // prefetch phase-3 first A-frags; fly under writeback + barrier
    if (w < 8) {
      p3a = ldnt(ws + WS_W2F + (((p3r * 8 + w) * 64 + l) << 4));
      p3b = ldnt(ws + WS_W2F + (((((p3r + 1) & 7) * 8 + w) * 64 + l) << 4));
    }

    const f32x4 accA[4] = {r0, r1, r2, r3};
    const int fb = w * 16 + q * 4;
    const float g0 = b1[fb], g1 = b1[fb + 1], g2 = b1[fb + 2], g3 = b1[fb + 3];
    const int kgd = fb >> 5, qd = (fb >> 3) & 3, ed = fb & 4;
#pragma unroll
    for (int rt = 0; rt < 4; ++rt) {
      const f32x4 v = accA[rt];
      uint2 p;
      p.x = f2bf(fmaxf(v[0] + g0, 0.f)) | ((unsigned)f2bf(fmaxf(v[1] + g1, 0.f)) << 16);
      p.y = f2bf(fmaxf(v[2] + g2, 0.f)) | ((unsigned)f2bf(fmaxf(v[3] + g3, 0.f)) << 16);
      *(uint2*)(h1frag + (((kgd * 4 + rt) * 64 + qd * 16 + cn) << 4) +
                (ed ? 8 : 0)) = p;
    }
  }

  __syncthreads();   // h1frag complete; outpart (FM) visible for phase-3 atomics

  // ---------------- Phase 3: h2 = relu(h1 @ W2 + b2); out = h2 @ W3 (+FM)
  // dedup'd: wave w<8 owns ft=w, all 4 rt tiles (W2 frags read once/block)
  if (w < 8) {
    const char* W2F = ws + WS_W2F;
    bf16x8 a0c = p3a;
    bf16x8 a0n = p3b;
    f32x4 d0 = zz, d1 = zz, d2 = zz, d3 = zz;
#pragma unroll
    for (int i = 0; i < 8; ++i) {
      const int kg = (p3r + i) & 7;
      const bf16x8 b0 = *(const bf16x8*)(h1frag + (((kg * 4 + 0) * 64 + l) << 4));
      const bf16x8 b1f = *(const bf16x8*)(h1frag + (((kg * 4 + 1) * 64 + l) << 4));
      const bf16x8 b2f = *(const bf16x8*)(h1frag + (((kg * 4 + 2) * 64 + l) << 4));
      const bf16x8 b3f = *(const bf16x8*)(h1frag + (((kg * 4 + 3) * 64 + l) << 4));
      bf16x8 a2;
      if (i < 6) {
        const int nkg = (p3r + i + 2) & 7;
        a2 = ldnt(W2F + (((nkg * 8 + w) * 64 + l) << 4));
      }
      d0 = mfma_bf16(a0c, b0,  d0);
      d1 = mfma_bf16(a0c, b1f, d1);
      d2 = mfma_bf16(a0c, b2f, d2);
      d3 = mfma_bf16(a0c, b3f, d3);
      a0c = a0n;
      if (i < 6) a0n = a2;
    }
    const int fb = w * 16 + q * 4;       // h2 feature strip (0..127)
    float bb[4], ww[4];
#pragma unroll
    for (int i = 0; i < 4; ++i) { bb[i] = b2[fb + i]; ww[i] = W3[fb + i]; }
    const f32x4 acc3[4] = {d0, d1, d2, d3};
#pragma unroll
    for (int j = 0; j < 4; ++j) {
      float p = 0.f;
#pragma unroll
      for (int reg = 0; reg < 4; ++reg)
        p += fmaxf(acc3[j][reg] + bb[reg], 0.f) * ww[reg];
      p += __shfl_xor(p, 16, 64);
      p += __shfl_xor(p, 32, 64);
      if (l < 16) atomicAdd(&outpart[j * 16 + cn], p);
    }
  }

  __syncthreads();
  if (tid < 64) out[row0 + tid] = outpart[tid];
}

// ---------------------------------------------------------------------------
extern "C" void kernel_launch(void* const* d_in, const int* in_sizes, int n_in,
                              void* d_out, int out_size, void* d_ws, size_t ws_size,
                              hipStream_t stream) {
  const float* movie = (const float*)d_in[0];
  const float* user  = (const float*)d_in[1];
  const float* Wm = (const float*)d_in[2];
  const float* bm = (const float*)d_in[3];
  const float* Wu = (const float*)d_in[4];
  const float* bu = (const float*)d_in[5];
  const float* W1 = (const float*)d_in[6];
  const float* b1 = (const float*)d_in[7];
  const float* W2 = (const float*)d_in[8];
  const float* b2 = (const float*)d_in[9];
  const float* W3 = (const float*)d_in[10];
  const float* b3 = (const float*)d_in[11];
  char* ws = (char*)d_ws;
  float* out = (float*)d_out;

  // allow >64KB dynamic LDS (idempotent, capture-safe)
  (void)hipFuncSetAttribute((const void*)deepfm_main,
                            hipFuncAttributeMaxDynamicSharedMemorySize, LDSB);

  deepfm_prep<<<225, 256, 0, stream>>>(Wm, bm, Wu, bu, W1, W2, b3, ws);
  deepfm_main<<<256, NTH, LDSB, stream>>>(movie, user, bm, bu, b1, b2, W3, ws, out);
}

// Round 5
// 129.538 us; speedup vs baseline: 1.0441x; 1.0441x over previous
//
#include <hip/hip_runtime.h>

// DeepFM fused kernel for MI355X (gfx950) — round 16.
// R15 with two changes:
//  1) REVERT nontemporal loads on ws A-frags: weights are reused across the
//     32 blocks/XCD via L2; nt (slc) marks them no-allocate/stream, so later
//     blocks re-fetch from HBM — plausible cause of R15's small regression.
//  2) v_cvt_pk_bf16_f32 for ALL f32->bf16 pair conversions (staging, T14
//     pfc, dense/h1 writebacks). Replaces the 7-op manual RNE pack with one
//     instruction; VALUBusy was 19% (~7.8 us) in R11, largely conversions.
// Kept from R14/R15: RB=64, NTH=1024, 1 block/CU, per-block K-rotation,
// T14 input prefetch with staggered conversion, aux dedup (waves wi<4),
// phase-3 dedup (8 waves x 4 rt), depth-1/2 A prefetch, setprio,
// waves_per_eu(4,4).

#define NTH 1024
#define RB  64

typedef __bf16 bf16x8 __attribute__((ext_vector_type(8)));
typedef float  f32x4  __attribute__((ext_vector_type(4)));

// workspace layout (bytes)
#define WS_WMF  0            // movie tower A-frags [16 kg][18 ft][64][16B]
#define WS_WUF  294912
#define WS_W1F  589824       // [16 kg][16 ft][64][16B]
#define WS_W2F  851968       // [8 kg][8 ft][64][16B]
#define WS_BIAS 917504       // fp32 bms[16] bus[16] badd

// LDS layout (bytes)
#define BPITCH  528          // 256 bf16 (half K) + 16B pad per row
#define L_BST   0            // bstage: 128 rows x 528 = 67584 (h1frag aliases)
#define L_DENSE 67584        // densefrag [16kg][4rt][64][16] = 65536
#define L_FM    133120       // fmbuf [2][64][17] f32 = 8704
#define L_ADD   141824       // addbuf [2][64] f32 = 512
#define L_OUT   142336       // outpart[64] f32 = 256
#define LDSB    142592

__device__ __forceinline__ unsigned short f2bf(float f) {
  unsigned u = __builtin_bit_cast(unsigned, f);
  u += 0x7FFFu + ((u >> 16) & 1u);           // RNE
  return (unsigned short)(u >> 16);
}

// one-instruction RNE pack of two f32 -> packed bf16 pair (lo=a, hi=b)
__device__ __forceinline__ unsigned cvtpk(float a, float b) {
  unsigned r;
  asm("v_cvt_pk_bf16_f32 %0, %1, %2" : "=v"(r) : "v"(a), "v"(b));
  return r;
}

__device__ __forceinline__ f32x4 mfma_bf16(bf16x8 a, bf16x8 b, f32x4 c) {
  return __builtin_amdgcn_mfma_f32_16x16x32_bf16(a, b, c, 0, 0, 0);
}

// ---------------------------------------------------------------------------
// Prep: fragment-ordered bf16 weights + bias aux. Tower features:
// f<256 raw col f; 256..271 = sum_i W[:, i*16+(f-256)] (FM col sums);
// 272 = W[:,256] (additive); 273..287 = 0.  4 units per 256-thread block.
// ---------------------------------------------------------------------------
extern "C" __global__ __launch_bounds__(256) void deepfm_prep(
    const float* __restrict__ Wm, const float* __restrict__ bm,
    const float* __restrict__ Wu, const float* __restrict__ bu,
    const float* __restrict__ W1, const float* __restrict__ W2,
    const float* __restrict__ b3, char* __restrict__ ws) {
  const int unit = blockIdx.x * 4 + (threadIdx.x >> 6);
  if (unit >= 897) return;
  const int l = threadIdx.x & 63;
  const int fi = l & 15, q = l >> 4;
  unsigned short h[8];
  if (unit < 576) {                      // towers: 2 x 16 kg x 18 ft
    const int t = unit / 288, rem = unit % 288;
    const int kg = rem / 18, ft = rem % 18;
    const float* W = t ? Wu : Wm;
    char* outp = ws + (t ? WS_WUF : WS_WMF);
    const int f = ft * 16 + fi;
#pragma unroll
    for (int e = 0; e < 8; ++e) {
      const int k = kg * 32 + q * 8 + e;
      float val;
      if (f < 256) val = W[k * 257 + f];
      else if (f < 272) {
        float s = 0.f;
#pragma unroll
        for (int i = 0; i < 16; ++i) s += W[k * 257 + i * 16 + (f - 256)];
        val = s;
      } else if (f == 272) val = W[k * 257 + 256];
      else val = 0.f;
      h[e] = f2bf(val);
    }
    uint4 o;
    o.x = h[0] | ((unsigned)h[1] << 16); o.y = h[2] | ((unsigned)h[3] << 16);
    o.z = h[4] | ((unsigned)h[5] << 16); o.w = h[6] | ((unsigned)h[7] << 16);
    *(uint4*)(outp + (((kg * 18 + ft) * 64 + l) << 4)) = o;
  } else if (unit < 832) {               // W1: 16 kg x 16 ft
    const int bb = unit - 576;
    const int kg = bb / 16, ft = bb % 16;
    const int f = ft * 16 + fi;
#pragma unroll
    for (int e = 0; e < 8; ++e) h[e] = f2bf(W1[(kg * 32 + q * 8 + e) * 256 + f]);
    uint4 o;
    o.x = h[0] | ((unsigned)h[1] << 16); o.y = h[2] | ((unsigned)h[3] << 16);
    o.z = h[4] | ((unsigned)h[5] << 16); o.w = h[6] | ((unsigned)h[7] << 16);
    *(uint4*)(ws + WS_W1F + (((kg * 16 + ft) * 64 + l) << 4)) = o;
  } else if (unit < 896) {               // W2: 8 kg x 8 ft
    const int bb = unit - 832;
    const int kg = bb / 8, ft = bb % 8;
    const int f = ft * 16 + fi;
#pragma unroll
    for (int e = 0; e < 8; ++e) h[e] = f2bf(W2[(kg * 32 + q * 8 + e) * 128 + f]);
    uint4 o;
    o.x = h[0] | ((unsigned)h[1] << 16); o.y = h[2] | ((unsigned)h[3] << 16);
    o.z = h[4] | ((unsigned)h[5] << 16); o.w = h[6] | ((unsigned)h[7] << 16);
    *(uint4*)(ws + WS_W2F + (((kg * 8 + ft) * 64 + l) << 4)) = o;
  } else {                               // bias aux
    float* aux = (float*)(ws + WS_BIAS);
    if (l < 16) {
      float s = 0.f;
      for (int i = 0; i < 16; ++i) s += bm[i * 16 + l];
      aux[l] = s;
    } else if (l < 32) {
      const int k = l - 16;
      float s = 0.f;
      for (int i = 0; i < 16; ++i) s += bu[i * 16 + k];
      aux[l] = s;
    } else if (l == 32) {
      aux[32] = bm[256] + bu[256] + b3[0];
    }
  }
}

// ---------------------------------------------------------------------------
// Main fused kernel. 64 rows/block, 16 waves.
// Phase 1: tw = w>>3 (tower), wi = w&7. Wave owns ft tiles {wi*2, wi*2+1},
// rt 0..3. Aux dedup: waves wi<4 own axi=wi&1 (0: FM col sums, 1: additive)
// for rt pair rtb=(wi>>1)*2. K in 2 staged halves (order rotated per
// block); T14 input prefetch with staggered cvt_pk conversion; compute-h1
// has 1-deep manual A prefetch.
// Phase 2: wave w owns ft=w (of 16), rt 0..3, depth-2 A prefetch.
// Phase 3: wave w<8 owns ft=w (of 8), rt 0..3, depth-2 A prefetch.
// ---------------------------------------------------------------------------
extern "C" __global__ __launch_bounds__(NTH)
__attribute__((amdgpu_waves_per_eu(4, 4))) void deepfm_main(
    const float* __restrict__ movie, const float* __restrict__ user,
    const float* __restrict__ bm, const float* __restrict__ bu,
    const float* __restrict__ b1, const float* __restrict__ b2,
    const float* __restrict__ W3, const char* __restrict__ ws,
    float* __restrict__ out) {
  extern __shared__ __align__(16) char lds[];
  char* const bstage    = lds + L_BST;     // 128 rows (both towers), half K
  char* const densefrag = lds + L_DENSE;   // [16kg][4rt][64][16]
  char* const h1frag    = lds + L_BST;     // phases 2/3 (aliases bstage)
  float* const fmbuf    = (float*)(lds + L_FM);   // [2][64][17]
  float* const addbuf   = (float*)(lds + L_ADD);  // [2][64]
  float* const outpart  = (float*)(lds + L_OUT);

  const int tid = threadIdx.x;
  const int w   = tid >> 6;        // 0..15
  const int l   = tid & 63;
  const int cn  = l & 15;
  const int q   = l >> 4;
  const int row0 = blockIdx.x * RB;

  const int tw   = w >> 3;         // tower this wave computes in phase 1
  const int wi   = w & 7;
  const int axi  = wi & 1;         // (wi<4) 0: FM col sums, 1: additive
  const int rtb  = (wi >> 1) * 2;  // (wi<4) rt pair base: 0 or 2

  // per-block rotation seeds (blocks on one XCD have distinct rot)
  const int rot  = (int)blockIdx.x >> 3;
  const int hord = rot & 1;                // phase-1 half order
  const int kk0  = (rot >> 1) & 7;         // phase-1 kgl start
  const int p2r  = rot & 15;               // phase-2 kg start
  const int p3r  = rot & 7;                // phase-3 kg start

  const f32x4 zz = {0.f, 0.f, 0.f, 0.f};
  const float* auxb = (const float*)(ws + WS_BIAS);

  bf16x8 p2a, p2b;   // phase-2 first two A-frags (prefetched across barrier)
  bf16x8 p3a, p3b;   // phase-3 first two A-frags

  // ---------------- Phase 1: both towers in parallel, K in 2 staged halves
  {
    const char* WF = ws + (tw ? WS_WUF : WS_WMF);
    const char* brow = bstage + tw * 64 * BPITCH;
    f32x4 a0r0 = zz, a0r1 = zz, a0r2 = zz, a0r3 = zz;
    f32x4 a1r0 = zz, a1r1 = zz, a1r2 = zz, a1r3 = zz;
    f32x4 axc0 = zz, axc1 = zz;

    const int h0 = hord, h1h = hord ^ 1;

    // stage half h0: 128 rows x 256 cols fp32 -> bf16, coalesced
#pragma unroll
    for (int p = 0; p < 8; ++p) {
      const int idx = p * 1024 + tid;    // float4 id
      const int rr = idx >> 6, f4 = idx & 63;
      const float* src = (rr >= 64) ? user : movie;
      const float4 v = *(const float4*)(src + (size_t)(row0 + (rr & 63)) * 512 +
                                        h0 * 256 + f4 * 4);
      uint2 o;
      o.x = cvtpk(v.x, v.y);
      o.y = cvtpk(v.z, v.w);
      *(uint2*)(bstage + rr * BPITCH + f4 * 8) = o;
    }
    __syncthreads();

    // T14: issue half-h1 global loads now; they land during compute(h0)
    float4 pf[8];
#pragma unroll
    for (int p = 0; p < 8; ++p) {
      const int idx = p * 1024 + tid;
      const int rr = idx >> 6, f4 = idx & 63;
      const float* src = (rr >= 64) ? user : movie;
      pf[p] = *(const float4*)(src + (size_t)(row0 + (rr & 63)) * 512 +
                               h1h * 256 + f4 * 4);
    }
    uint2 pfc[8];

    // compute half h0; in-iteration A loads; staggered pf conversion
#pragma unroll
    for (int i = 0; i < 8; ++i) {
      const int kgl = (kk0 + i) & 7;
      const int kg  = h0 * 8 + kgl;
      const bf16x8 bf0 = *(const bf16x8*)(brow + cn * BPITCH + kgl * 64 + q * 16);
      const bf16x8 bf1 = *(const bf16x8*)(brow + (16 + cn) * BPITCH + kgl * 64 + q * 16);
      const bf16x8 bf2 = *(const bf16x8*)(brow + (32 + cn) * BPITCH + kgl * 64 + q * 16);
      const bf16x8 bf3 = *(const bf16x8*)(brow + (48 + cn) * BPITCH + kgl * 64 + q * 16);
      const bf16x8 A0 = *(const bf16x8*)(WF + (((kg * 18 + wi * 2 + 0) * 64 + l) << 4));
      const bf16x8 A1 = *(const bf16x8*)(WF + (((kg * 18 + wi * 2 + 1) * 64 + l) << 4));
      bf16x8 AX;
      if (wi < 4) AX = *(const bf16x8*)(WF + (((kg * 18 + 16 + axi) * 64 + l) << 4));
      __builtin_amdgcn_s_setprio(1);
      a0r0 = mfma_bf16(A0, bf0, a0r0);  a0r1 = mfma_bf16(A0, bf1, a0r1);
      a0r2 = mfma_bf16(A0, bf2, a0r2);  a0r3 = mfma_bf16(A0, bf3, a0r3);
      a1r0 = mfma_bf16(A1, bf0, a1r0);  a1r1 = mfma_bf16(A1, bf1, a1r1);
      a1r2 = mfma_bf16(A1, bf2, a1r2);  a1r3 = mfma_bf16(A1, bf3, a1r3);
      if (wi < 4) {
        const bf16x8 bs0 = rtb ? bf2 : bf0;
        const bf16x8 bs1 = rtb ? bf3 : bf1;
        axc0 = mfma_bf16(AX, bs0, axc0);
        axc1 = mfma_bf16(AX, bs1, axc1);
      }
      __builtin_amdgcn_s_setprio(0);
      if (i >= 1) {
        const int j = i - 1;               // static after unroll
        pfc[j].x = cvtpk(pf[j].x, pf[j].y);
        pfc[j].y = cvtpk(pf[j].z, pf[j].w);
      }
    }
    pfc[7].x = cvtpk(pf[7].x, pf[7].y);
    pfc[7].y = cvtpk(pf[7].z, pf[7].w);

    __syncthreads();   // half-h0 reads done before overwrite

    // issue first h1 kstep's A-frags; they fly under the LDS writes+barrier
    bf16x8 A0c = *(const bf16x8*)(WF + ((((h1h * 8 + kk0) * 18 + wi * 2 + 0) * 64 + l) << 4));
    bf16x8 A1c = *(const bf16x8*)(WF + ((((h1h * 8 + kk0) * 18 + wi * 2 + 1) * 64 + l) << 4));

    // write prefetched half h1 (already bf16) to LDS
#pragma unroll
    for (int p = 0; p < 8; ++p) {
      const int idx = p * 1024 + tid;
      const int rr = idx >> 6, f4 = idx & 63;
      *(uint2*)(bstage + rr * BPITCH + f4 * 8) = pfc[p];
    }
    __syncthreads();

    // compute half h1: manual 1-deep A prefetch (pf regs dead now)
#pragma unroll
    for (int i = 0; i < 8; ++i) {
      const int kgl = (kk0 + i) & 7;
      const int kg  = h1h * 8 + kgl;
      const bf16x8 bf0 = *(const bf16x8*)(brow + cn * BPITCH + kgl * 64 + q * 16);
      const bf16x8 bf1 = *(const bf16x8*)(brow + (16 + cn) * BPITCH + kgl * 64 + q * 16);
      const bf16x8 bf2 = *(const bf16x8*)(brow + (32 + cn) * BPITCH + kgl * 64 + q * 16);
      const bf16x8 bf3 = *(const bf16x8*)(brow + (48 + cn) * BPITCH + kgl * 64 + q * 16);
      bf16x8 AX;
      if (wi < 4) AX = *(const bf16x8*)(WF + (((kg * 18 + 16 + axi) * 64 + l) << 4));
      bf16x8 A0n, A1n;
      if (i < 7) {
        const int nkg = h1h * 8 + ((kk0 + i + 1) & 7);
        A0n = *(const bf16x8*)(WF + (((nkg * 18 + wi * 2 + 0) * 64 + l) << 4));
        A1n = *(const bf16x8*)(WF + (((nkg * 18 + wi * 2 + 1) * 64 + l) << 4));
      } else {
        A0n = A0c; A1n = A1c;
      }
      __builtin_amdgcn_s_setprio(1);
      a0r0 = mfma_bf16(A0c, bf0, a0r0);  a0r1 = mfma_bf16(A0c, bf1, a0r1);
      a0r2 = mfma_bf16(A0c, bf2, a0r2);  a0r3 = mfma_bf16(A0c, bf3, a0r3);
      a1r0 = mfma_bf16(A1c, bf0, a1r0);  a1r1 = mfma_bf16(A1c, bf1, a1r1);
      a1r2 = mfma_bf16(A1c, bf2, a1r2);  a1r3 = mfma_bf16(A1c, bf3, a1r3);
      if (wi < 4) {
        const bf16x8 bs0 = rtb ? bf2 : bf0;
        const bf16x8 bs1 = rtb ? bf3 : bf1;
        axc0 = mfma_bf16(AX, bs0, axc0);
        axc1 = mfma_bf16(AX, bs1, axc1);
      }
      __builtin_amdgcn_s_setprio(0);
      A0c = A0n; A1c = A1n;
    }

    // prefetch phase-2 first A-frags; fly under writeback + barrier + FM
    p2a = *(const bf16x8*)(ws + WS_W1F + (((p2r * 16 + w) * 64 + l) << 4));
    p2b = *(const bf16x8*)(ws + WS_W1F + (((((p2r + 1) & 15) * 16 + w) * 64 + l) << 4));

    // writeback dense feats (+tower bias, no relu) into densefrag
    const float* bt = tw ? bu : bm;
    const f32x4 accA[2][4] = {{a0r0, a0r1, a0r2, a0r3}, {a1r0, a1r1, a1r2, a1r3}};
#pragma unroll
    for (int s = 0; s < 2; ++s) {
      const int ft = wi * 2 + s;
      const int fb = ft * 16 + q * 4;
      const float g0 = bt[fb], g1 = bt[fb + 1], g2 = bt[fb + 2], g3 = bt[fb + 3];
      const int kd = tw * 256 + fb;
      const int kgd = kd >> 5, qd = (kd >> 3) & 3, ed = kd & 4;
#pragma unroll
      for (int rt = 0; rt < 4; ++rt) {
        const f32x4 v = accA[s][rt];
        uint2 p;
        p.x = cvtpk(v[0] + g0, v[1] + g1);
        p.y = cvtpk(v[2] + g2, v[3] + g3);
        *(uint2*)(densefrag + (((kgd * 4 + rt) * 64 + qd * 16 + cn) << 4) +
                  (ed ? 8 : 0)) = p;
      }
    }

    // aux writeback (dedup'd): wi<4 own rt pair {rtb, rtb+1}
    if (wi < 4) {
      if (axi == 0) {
#pragma unroll
        for (int reg = 0; reg < 4; ++reg) {
          fmbuf[(tw * 64 + rtb * 16 + cn) * 17 + (q * 4 + reg)] = axc0[reg];
          fmbuf[(tw * 64 + (rtb + 1) * 16 + cn) * 17 + (q * 4 + reg)] = axc1[reg];
        }
      } else if (q == 0) {
        addbuf[tw * 64 + rtb * 16 + cn] = axc0[0];
        addbuf[tw * 64 + (rtb + 1) * 16 + cn] = axc1[0];
      }
    }
  }

  __syncthreads();   // densefrag + fmbuf/addbuf complete; bstage dead

  // ---------------- FM epilogue: out_partial = <ms+bms, us+bus> + additive
  if (tid < 64) {
    float p = 0.f;
#pragma unroll
    for (int k = 0; k < 16; ++k)
      p += (fmbuf[tid * 17 + k] + auxb[k]) *
           (fmbuf[(64 + tid) * 17 + k] + auxb[16 + k]);
    outpart[tid] = p + addbuf[tid] + addbuf[64 + tid] + auxb[32];
  }

  // ---------------- Phase 2: h1 = relu(all_dense @ W1 + b1)
  {
    const char* W1F = ws + WS_W1F;
    bf16x8 a0c = p2a;
    bf16x8 a0n = p2b;
    f32x4 r0 = zz, r1 = zz, r2 = zz, r3 = zz;
#pragma unroll
    for (int i = 0; i < 16; ++i) {
      const int kg = (p2r + i) & 15;
      const bf16x8 b0 = *(const bf16x8*)(densefrag + (((kg * 4 + 0) * 64 + l) << 4));
      const bf16x8 b1f = *(const bf16x8*)(densefrag + (((kg * 4 + 1) * 64 + l) << 4));
      const bf16x8 b2f = *(const bf16x8*)(densefrag + (((kg * 4 + 2) * 64 + l) << 4));
      const bf16x8 b3f = *(const bf16x8*)(densefrag + (((kg * 4 + 3) * 64 + l) << 4));
      bf16x8 a2;
      if (i < 14) {
        const int nkg = (p2r + i + 2) & 15;
        a2 = *(const bf16x8*)(W1F + (((nkg * 16 + w) * 64 + l) << 4));
      }
      __builtin_amdgcn_s_setprio(1);
      r0 = mfma_bf16(a0c, b0,  r0);
      r1 = mfma_bf16(a0c, b1f, r1);
      r2 = mfma_bf16(a0c, b2f, r2);
      r3 = mfma_bf16(a0c, b3f, r3);
      __builtin_amdgcn_s_setprio(0);
      a0c = a0n;
      if (i < 14) a0n = a2;
    }

    // prefetch phase-3 first A-frags; fly under writeback + barrier
    if (w < 8) {
      p3a = *(const bf16x8*)(ws + WS_W2F + (((p3r * 8 + w) * 64 + l) << 4));
      p3b = *(const bf16x8*)(ws + WS_W2F + (((((p3r + 1) & 7) * 8 + w) * 64 + l) << 4));
    }

    const f32x4 accA[4] = {r0, r1, r2, r3};
    const int fb = w * 16 + q * 4;
    const float g0 = b1[fb], g1 = b1[fb + 1], g2 = b1[fb + 2], g3 = b1[fb + 3];
    const int kgd = fb >> 5, qd = (fb >> 3) & 3, ed = fb & 4;
#pragma unroll
    for (int rt = 0; rt < 4; ++rt) {
      const f32x4 v = accA[rt];
      uint2 p;
      p.x = cvtpk(fmaxf(v[0] + g0, 0.f), fmaxf(v[1] + g1, 0.f));
      p.y = cvtpk(fmaxf(v[2] + g2, 0.f), fmaxf(v[3] + g3, 0.f));
      *(uint2*)(h1frag + (((kgd * 4 + rt) * 64 + qd * 16 + cn) << 4) +
                (ed ? 8 : 0)) = p;
    }
  }

  __syncthreads();   // h1frag complete; outpart (FM) visible for phase-3 atomics

  // ---------------- Phase 3: h2 = relu(h1 @ W2 + b2); out = h2 @ W3 (+FM)
  // dedup'd: wave w<8 owns ft=w, all 4 rt tiles (W2 frags read once/block)
  if (w < 8) {
    const char* W2F = ws + WS_W2F;
    bf16x8 a0c = p3a;
    bf16x8 a0n = p3b;
    f32x4 d0 = zz, d1 = zz, d2 = zz, d3 = zz;
#pragma unroll
    for (int i = 0; i < 8; ++i) {
      const int kg = (p3r + i) & 7;
      const bf16x8 b0 = *(const bf16x8*)(h1frag + (((kg * 4 + 0) * 64 + l) << 4));
      const bf16x8 b1f = *(const bf16x8*)(h1frag + (((kg * 4 + 1) * 64 + l) << 4));
      const bf16x8 b2f = *(const bf16x8*)(h1frag + (((kg * 4 + 2) * 64 + l) << 4));
      const bf16x8 b3f = *(const bf16x8*)(h1frag + (((kg * 4 + 3) * 64 + l) << 4));
      bf16x8 a2;
      if (i < 6) {
        const int nkg = (p3r + i + 2) & 7;
        a2 = *(const bf16x8*)(W2F + (((nkg * 8 + w) * 64 + l) << 4));
      }
      d0 = mfma_bf16(a0c, b0,  d0);
      d1 = mfma_bf16(a0c, b1f, d1);
      d2 = mfma_bf16(a0c, b2f, d2);
      d3 = mfma_bf16(a0c, b3f, d3);
      a0c = a0n;
      if (i < 6) a0n = a2;
    }
    const int fb = w * 16 + q * 4;       // h2 feature strip (0..127)
    float bb[4], ww[4];
#pragma unroll
    for (int i = 0; i < 4; ++i) { bb[i] = b2[fb + i]; ww[i] = W3[fb + i]; }
    const f32x4 acc3[4] = {d0, d1, d2, d3};
#pragma unroll
    for (int j = 0; j < 4; ++j) {
      float p = 0.f;
#pragma unroll
      for (int reg = 0; reg < 4; ++reg)
        p += fmaxf(acc3[j][reg] + bb[reg], 0.f) * ww[reg];
      p += __shfl_xor(p, 16, 64);
      p += __shfl_xor(p, 32, 64);
      if (l < 16) atomicAdd(&outpart[j * 16 + cn], p);
    }
  }

  __syncthreads();
  if (tid < 64) out[row0 + tid] = outpart[tid];
}

// ---------------------------------------------------------------------------
extern "C" void kernel_launch(void* const* d_in, const int* in_sizes, int n_in,
                              void* d_out, int out_size, void* d_ws, size_t ws_size,
                              hipStream_t stream) {
  const float* movie = (const float*)d_in[0];
  const float* user  = (const float*)d_in[1];
  const float* Wm = (const float*)d_in[2];
  const float* bm = (const float*)d_in[3];
  const float* Wu = (const float*)d_in[4];
  const float* bu = (const float*)d_in[5];
  const float* W1 = (const float*)d_in[6];
  const float* b1 = (const float*)d_in[7];
  const float* W2 = (const float*)d_in[8];
  const float* b2 = (const float*)d_in[9];
  const float* W3 = (const float*)d_in[10];
  const float* b3 = (const float*)d_in[11];
  char* ws = (char*)d_ws;
  float* out = (float*)d_out;

  // allow >64KB dynamic LDS (idempotent, capture-safe)
  (void)hipFuncSetAttribute((const void*)deepfm_main,
                            hipFuncAttributeMaxDynamicSharedMemorySize, LDSB);

  deepfm_prep<<<225, 256, 0, stream>>>(Wm, bm, Wu, bu, W1, W2, b3, ws);
  deepfm_main<<<256, NTH, LDSB, stream>>>(movie, user, bm, bu, b1, b2, W3, ws, out);
}